// Round 8
// baseline (482.300 us; speedup 1.0000x reference)
//
#include <hip/hip_runtime.h>

// GAT aggregate, two-phase — R8 = R5 EXACT + ctx_kernel launched TWICE.
// Purpose: measure the phase split (T8 - T5 = ctx duration) since rocprof
// top-5 is saturated by 480us harness fill kernels. ctx_kernel is idempotent
// (reads self/neigh only, writes io), so the duplicate launch leaves the
// output bit-identical and graph-capture-safe.
//
//   Phase 1 (ctx_kernel):  ctx[n] = softmax(<self_n,[neigh_n;self_n]>) . [neigh_n;self_n]
//   Phase 2 (mlp_kernel):  d_out[n] = relu(ctx[n] @ W), in place.

constexpr int K    = 16;
constexpr int D    = 128;
constexpr int DOUT = 128;
constexpr int NPW  = 8;   // nodes per wave-iteration in phase 2

__device__ __forceinline__ float wave_allsum(float x) {
    #pragma unroll
    for (int off = 32; off; off >>= 1)
        x += __shfl_xor(x, off);
    return x;
}

// ---------------- Phase 1: attention context (no LDS, no W) — R5 exact ----------------
__launch_bounds__(256, 4)
__global__ void ctx_kernel(const float* __restrict__ self_vecs,
                           const float* __restrict__ neigh_vecs,
                           float* __restrict__ io,
                           int n_nodes) {
    const int lane = threadIdx.x & 63;
    const int n = (int)((blockIdx.x * blockDim.x + threadIdx.x) >> 6);
    if (n >= n_nodes) return;

    const float* nbp = neigh_vecs + (size_t)n * (K * D) + 2 * lane;
    float2 v[K];
    #pragma unroll
    for (int k = 0; k < K; ++k) v[k] = *(const float2*)(nbp + (size_t)k * D);
    const float2 s = *(const float2*)(self_vecs + (size_t)n * D + 2 * lane);

    float m = wave_allsum(s.x * s.x + s.y * s.y);
    float sum = 1.f, cx = s.x, cy = s.y;
    #pragma unroll
    for (int k = 0; k < K; ++k) {
        const float d  = wave_allsum(s.x * v[k].x + s.y * v[k].y);
        const float mn = fmaxf(m, d);
        const float sc = __expf(m - mn);
        const float e  = __expf(d - mn);
        sum = sum * sc + e;
        cx  = cx * sc + e * v[k].x;
        cy  = cy * sc + e * v[k].y;
        m = mn;
    }
    const float inv = 1.f / sum;
    *(float2*)(io + (size_t)n * D + 2 * lane) = make_float2(cx * inv, cy * inv);
}

// ---------------- Phase 2: in-place row MLP with relu — R5 exact ----------------
__launch_bounds__(256, 2)
__global__ void mlp_kernel(const float* __restrict__ W,
                           float* __restrict__ io,
                           int n_nodes, int total_waves) {
    // Interleaved W: float4 slot s = p*64 + l holds
    //   { W[2p][2l], W[2p][2l+1], W[2p+1][2l], W[2p+1][2l+1] }
    __shared__ float Ws[D * DOUT];  // 64 KiB -> 2 blocks/CU

    const int tid = threadIdx.x;
    for (int sI = tid; sI < (D * DOUT) / 4; sI += blockDim.x) {
        const int p = sI >> 6;
        const int l = sI & 63;
        const float* r0 = W + (size_t)(2 * p) * DOUT + 2 * l;
        const float2 a = *(const float2*)r0;
        const float2 b = *(const float2*)(r0 + DOUT);
        ((float4*)Ws)[sI] = make_float4(a.x, a.y, b.x, b.y);
    }
    __syncthreads();

    const int lane = tid & 63;
    const int wave = blockIdx.x * (blockDim.x >> 6) + (tid >> 6);

    for (int base = wave * NPW; base < n_nodes; base += total_waves * NPW) {
        float a0[NPW], a1[NPW];
        #pragma unroll
        for (int j = 0; j < NPW; ++j) { a0[j] = 0.f; a1[j] = 0.f; }

        #pragma unroll 8
        for (int p = 0; p < D / 2; ++p) {
            const float4 w = ((const float4*)Ws)[p * 64 + lane];
            #pragma unroll
            for (int j = 0; j < NPW; ++j) {
                const int n = (base + j < n_nodes) ? base + j : n_nodes - 1;
                const float2 c = *(const float2*)(io + (size_t)n * D + 2 * p);
                a0[j] += c.x * w.x + c.y * w.z;
                a1[j] += c.x * w.y + c.y * w.w;
            }
        }
        #pragma unroll
        for (int j = 0; j < NPW; ++j) {
            if (base + j < n_nodes)
                *(float2*)(io + (size_t)(base + j) * DOUT + 2 * lane) =
                    make_float2(fmaxf(a0[j], 0.f), fmaxf(a1[j], 0.f));
        }
    }
}

extern "C" void kernel_launch(void* const* d_in, const int* in_sizes, int n_in,
                              void* d_out, int out_size, void* d_ws, size_t ws_size,
                              hipStream_t stream) {
    const float* self_vecs = (const float*)d_in[0];
    const float* neigh     = (const float*)d_in[1];
    const float* W         = (const float*)d_in[2];
    float* io = (float*)d_out;

    const int n_nodes = in_sizes[0] / D;  // 100000

    // Phase 1 launched TWICE (idempotent) — T_total minus R5's 318.5us = ctx time.
    {
        const int tpb = 256;
        const int blocks = (n_nodes * 64 + tpb - 1) / tpb;  // 25000
        ctx_kernel<<<dim3(blocks), dim3(tpb), 0, stream>>>(
            self_vecs, neigh, io, n_nodes);
        ctx_kernel<<<dim3(blocks), dim3(tpb), 0, stream>>>(
            self_vecs, neigh, io, n_nodes);
    }
    // Phase 2: R5 exact
    {
        const int tpb = 256;
        const int blocks = 512;
        const int total_waves = blocks * (tpb / 64);
        mlp_kernel<<<dim3(blocks), dim3(tpb), 0, stream>>>(
            W, io, n_nodes, total_waves);
    }
}

// Round 9
// 270.413 us; speedup vs baseline: 1.7836x; 1.7836x over previous
//
#include <hip/hip_runtime.h>

// GAT aggregate, two-phase: N=100000, K=16, D=128, DOUT=128, fp32.
//   Phase 1 (ctx_kernel):  ctx[n] = softmax(<self_n,[neigh_n;self_n]>) . [neigh_n;self_n]
//                          -> written into d_out  (R5 exact, measured 164us ~ 5.6 TB/s)
//   Phase 2 (mlp_kernel):  d_out[n] = relu(ctx[n] @ W), in place.
//
// R9 changes phase 2 ONLY (A/B vs R5's 318.5us total, mlp measured ~155us):
// the old inner loop issued 512 wave-uniform GLOBAL loads per wave-iteration
// (all lanes fetching the same 8B, ~200-400cyc each, few outstanding) -- the
// 4KB of ctx data is now staged per-wave into LDS with 8 coalesced loads +
// 8 ds_writes, then consumed via uniform ds_read_b128 broadcasts (conflict-
// free, no VMEM latency on the critical path). LDS 64KiB(W)+16KiB(ctx)=80KiB
// -> still 2 blocks/CU, 8 waves/CU, same occupancy as R5.
//
// NOTE: __launch_bounds__ arg2 observed CUDA-style (min BLOCKS/CU) on this
// toolchain (R2: (512,4) -> 64-VGPR cap + catastrophic spill).

constexpr int K    = 16;
constexpr int D    = 128;
constexpr int DOUT = 128;
constexpr int NPW  = 8;   // nodes per wave-iteration in phase 2

__device__ __forceinline__ float wave_allsum(float x) {
    #pragma unroll
    for (int off = 32; off; off >>= 1)
        x += __shfl_xor(x, off);
    return x;
}

// ---------------- Phase 1: attention context (no LDS, no W) — R5 exact ----------------
__launch_bounds__(256, 4)
__global__ void ctx_kernel(const float* __restrict__ self_vecs,
                           const float* __restrict__ neigh_vecs,
                           float* __restrict__ io,
                           int n_nodes) {
    const int lane = threadIdx.x & 63;
    const int n = (int)((blockIdx.x * blockDim.x + threadIdx.x) >> 6);
    if (n >= n_nodes) return;

    const float* nbp = neigh_vecs + (size_t)n * (K * D) + 2 * lane;
    float2 v[K];
    #pragma unroll
    for (int k = 0; k < K; ++k) v[k] = *(const float2*)(nbp + (size_t)k * D);
    const float2 s = *(const float2*)(self_vecs + (size_t)n * D + 2 * lane);

    float m = wave_allsum(s.x * s.x + s.y * s.y);
    float sum = 1.f, cx = s.x, cy = s.y;
    #pragma unroll
    for (int k = 0; k < K; ++k) {
        const float d  = wave_allsum(s.x * v[k].x + s.y * v[k].y);
        const float mn = fmaxf(m, d);
        const float sc = __expf(m - mn);
        const float e  = __expf(d - mn);
        sum = sum * sc + e;
        cx  = cx * sc + e * v[k].x;
        cy  = cy * sc + e * v[k].y;
        m = mn;
    }
    const float inv = 1.f / sum;
    *(float2*)(io + (size_t)n * D + 2 * lane) = make_float2(cx * inv, cy * inv);
}

// ---------------- Phase 2: in-place row MLP with relu ----------------
__launch_bounds__(256, 2)
__global__ void mlp_kernel(const float* __restrict__ W,
                           float* __restrict__ io,
                           int n_nodes, int total_waves) {
    // Interleaved W: float4 slot s = p*64 + l holds
    //   { W[2p][2l], W[2p][2l+1], W[2p+1][2l], W[2p+1][2l+1] }  (R1-verified)
    __shared__ float Ws[D * DOUT];                    // 64 KiB
    __shared__ __align__(16) float Cs[4][NPW][D];     // 16 KiB: per-wave ctx stage

    const int tid = threadIdx.x;
    for (int sI = tid; sI < (D * DOUT) / 4; sI += blockDim.x) {
        const int p = sI >> 6;
        const int l = sI & 63;
        const float* r0 = W + (size_t)(2 * p) * DOUT + 2 * l;
        const float2 a = *(const float2*)r0;
        const float2 b = *(const float2*)(r0 + DOUT);
        ((float4*)Ws)[sI] = make_float4(a.x, a.y, b.x, b.y);
    }
    __syncthreads();

    const int lane = tid & 63;
    const int wid  = tid >> 6;
    const int wave = blockIdx.x * (blockDim.x >> 6) + wid;

    for (int base = wave * NPW; base < n_nodes; base += total_waves * NPW) {
        // ---- stage 8 ctx rows: 8 coalesced b64 loads + 8 ds_writes (same wave,
        //      no barrier needed; duplicate clamped rows write identical bytes) ----
        #pragma unroll
        for (int j = 0; j < NPW; ++j) {
            const int n = (base + j < n_nodes) ? base + j : n_nodes - 1;
            const float2 c = *(const float2*)(io + (size_t)n * D + 2 * lane);
            *(float2*)&Cs[wid][j][2 * lane] = c;
        }

        float a0[NPW], a1[NPW];
        #pragma unroll
        for (int j = 0; j < NPW; ++j) { a0[j] = 0.f; a1[j] = 0.f; }

        // ---- two p-steps per uniform b128 broadcast read of ctx ----
        #pragma unroll 4
        for (int p = 0; p < D / 2; p += 2) {
            const float4 w0 = ((const float4*)Ws)[p * 64 + lane];
            const float4 w1 = ((const float4*)Ws)[(p + 1) * 64 + lane];
            #pragma unroll
            for (int j = 0; j < NPW; ++j) {
                const float4 c = *(const float4*)&Cs[wid][j][2 * p];  // uniform -> broadcast
                a0[j] += c.x * w0.x + c.y * w0.z + c.z * w1.x + c.w * w1.z;
                a1[j] += c.x * w0.y + c.y * w0.w + c.z * w1.y + c.w * w1.w;
            }
        }
        #pragma unroll
        for (int j = 0; j < NPW; ++j) {
            if (base + j < n_nodes)
                *(float2*)(io + (size_t)(base + j) * DOUT + 2 * lane) =
                    make_float2(fmaxf(a0[j], 0.f), fmaxf(a1[j], 0.f));
        }
    }
}

extern "C" void kernel_launch(void* const* d_in, const int* in_sizes, int n_in,
                              void* d_out, int out_size, void* d_ws, size_t ws_size,
                              hipStream_t stream) {
    const float* self_vecs = (const float*)d_in[0];
    const float* neigh     = (const float*)d_in[1];
    const float* W         = (const float*)d_in[2];
    float* io = (float*)d_out;

    const int n_nodes = in_sizes[0] / D;  // 100000

    // Phase 1: one wave per node (R5 exact)
    {
        const int tpb = 256;
        const int blocks = (n_nodes * 64 + tpb - 1) / tpb;  // 25000
        ctx_kernel<<<dim3(blocks), dim3(tpb), 0, stream>>>(
            self_vecs, neigh, io, n_nodes);
    }
    // Phase 2: grid-stride, 8 nodes per wave-iteration, ctx via LDS broadcast
    {
        const int tpb = 256;
        const int blocks = 512;
        const int total_waves = blocks * (tpb / 64);
        mlp_kernel<<<dim3(blocks), dim3(tpb), 0, stream>>>(
            W, io, n_nodes, total_waves);
    }
}

// Round 10
// 267.452 us; speedup vs baseline: 1.8033x; 1.0111x over previous
//
#include <hip/hip_runtime.h>

// GAT aggregate, two-phase: N=100000, K=16, D=128, DOUT=128, fp32.
//   Phase 1 (ctx_kernel): ctx[n] = softmax(<self_n,[neigh;self]>).[neigh;self]
//                         -> d_out (R5 exact; measured ~164us = 5.6 TB/s)
//   Phase 2 (mlp_mfma):   d_out[n] = relu(ctx[n] @ W) via bf16 MFMA, in place.
//
// R10 changes phase 2 ONLY. R9 showed phase 2 (~106us) is fp32-VALU-issue-
// bound (2048 FMA/wave-iter on the vector pipe; no fp32 MFMA on CDNA4).
// Move the matmul to the matrix pipe: mfma_f32_16x16x32_bf16, ctx split into
// hi+lo bf16 (2 MFMAs -> ~fp32-accurate ctx), W rounded once to bf16
// (worst-case err ~0.06 << 0.108 threshold). A = W^T (M=outcol) staged in LDS
// bf16 with rows padded to 136 shorts (272B) for uniform bank spread;
// B = ctx (N=node) loaded straight from global with in-register cvt.
// 100000 = 6250 exact 16-node tiles, no tail. LDS 34.8KB -> 4 blocks/CU.

constexpr int K    = 16;
constexpr int D    = 128;
constexpr int DOUT = 128;
constexpr int WT_PITCH = 136;   // 128 + 8 pad (shorts) = 272B rows

typedef short bfrag  __attribute__((ext_vector_type(8)));
typedef float afrag  __attribute__((ext_vector_type(4)));

__device__ __forceinline__ unsigned short f2bf(float f) {
    union { float f; unsigned u; } v; v.f = f;
    const unsigned r = v.u + 0x7FFF + ((v.u >> 16) & 1);   // RNE
    return (unsigned short)(r >> 16);
}
__device__ __forceinline__ float bf2f(unsigned short b) {
    union { unsigned u; float f; } v; v.u = ((unsigned)b) << 16;
    return v.f;
}

__device__ __forceinline__ float wave_allsum(float x) {
    #pragma unroll
    for (int off = 32; off; off >>= 1)
        x += __shfl_xor(x, off);
    return x;
}

// ---------------- Phase 1: attention context (no LDS, no W) — R5 exact ----------------
__launch_bounds__(256, 4)
__global__ void ctx_kernel(const float* __restrict__ self_vecs,
                           const float* __restrict__ neigh_vecs,
                           float* __restrict__ io,
                           int n_nodes) {
    const int lane = threadIdx.x & 63;
    const int n = (int)((blockIdx.x * blockDim.x + threadIdx.x) >> 6);
    if (n >= n_nodes) return;

    const float* nbp = neigh_vecs + (size_t)n * (K * D) + 2 * lane;
    float2 v[K];
    #pragma unroll
    for (int k = 0; k < K; ++k) v[k] = *(const float2*)(nbp + (size_t)k * D);
    const float2 s = *(const float2*)(self_vecs + (size_t)n * D + 2 * lane);

    float m = wave_allsum(s.x * s.x + s.y * s.y);
    float sum = 1.f, cx = s.x, cy = s.y;
    #pragma unroll
    for (int k = 0; k < K; ++k) {
        const float d  = wave_allsum(s.x * v[k].x + s.y * v[k].y);
        const float mn = fmaxf(m, d);
        const float sc = __expf(m - mn);
        const float e  = __expf(d - mn);
        sum = sum * sc + e;
        cx  = cx * sc + e * v[k].x;
        cy  = cy * sc + e * v[k].y;
        m = mn;
    }
    const float inv = 1.f / sum;
    *(float2*)(io + (size_t)n * D + 2 * lane) = make_float2(cx * inv, cy * inv);
}

// ---------------- Phase 2: in-place row MLP via bf16 MFMA ----------------
__launch_bounds__(256, 4)
__global__ void mlp_mfma(const float* __restrict__ W,
                         float* __restrict__ io,
                         int n_tiles, int total_waves) {
    // Wt[m][k] = bf16(W[k][m]): A-operand (M=outcol), padded rows for banks
    __shared__ __align__(16) unsigned short Wt[DOUT][WT_PITCH];

    const int tid = threadIdx.x;
    for (int e = tid; e < D * DOUT; e += blockDim.x) {
        const int k = e >> 7, m = e & 127;     // W row-major [k][dout]
        Wt[m][k] = f2bf(W[e]);
    }
    __syncthreads();

    const int lane = tid & 63;
    const int nl   = lane & 15;   // node-in-tile (B col) / A row-in-tile
    const int kb   = lane >> 4;   // k-subgroup (8 elems each)
    const int wave = blockIdx.x * (blockDim.x >> 6) + (tid >> 6);

    for (int t = wave; t < n_tiles; t += total_waves) {
        const int node0 = t * 16;
        afrag acc[8];
        #pragma unroll
        for (int i = 0; i < 8; ++i)
            #pragma unroll
            for (int r = 0; r < 4; ++r) acc[i][r] = 0.f;

        #pragma unroll
        for (int kc = 0; kc < 4; ++kc) {
            // B-frag: ctx[node0+nl][kc*32 + kb*8 + i], hi/lo bf16 split
            const float* cp = io + (size_t)(node0 + nl) * D + kc * 32 + kb * 8;
            const float4 c0 = *(const float4*)cp;
            const float4 c1 = *(const float4*)(cp + 4);
            const float cf[8] = {c0.x, c0.y, c0.z, c0.w, c1.x, c1.y, c1.z, c1.w};
            bfrag ch, cl;
            #pragma unroll
            for (int i = 0; i < 8; ++i) {
                const unsigned short h = f2bf(cf[i]);
                ch[i] = (short)h;
                cl[i] = (short)f2bf(cf[i] - bf2f(h));
            }
            #pragma unroll
            for (int nt = 0; nt < 8; ++nt) {
                const bfrag a = *(const bfrag*)&Wt[nt * 16 + nl][kc * 32 + kb * 8];
                acc[nt] = __builtin_amdgcn_mfma_f32_16x16x32_bf16(a, ch, acc[nt], 0, 0, 0);
                acc[nt] = __builtin_amdgcn_mfma_f32_16x16x32_bf16(a, cl, acc[nt], 0, 0, 0);
            }
        }
        // D: col=lane&15=node, row=(lane>>4)*4+r=outcol (m89-verified layout)
        float* orow = io + (size_t)(node0 + nl) * DOUT + kb * 4;
        #pragma unroll
        for (int nt = 0; nt < 8; ++nt) {
            const float4 v = make_float4(fmaxf(acc[nt][0], 0.f), fmaxf(acc[nt][1], 0.f),
                                         fmaxf(acc[nt][2], 0.f), fmaxf(acc[nt][3], 0.f));
            *(float4*)(orow + nt * 16) = v;
        }
    }
}

extern "C" void kernel_launch(void* const* d_in, const int* in_sizes, int n_in,
                              void* d_out, int out_size, void* d_ws, size_t ws_size,
                              hipStream_t stream) {
    const float* self_vecs = (const float*)d_in[0];
    const float* neigh     = (const float*)d_in[1];
    const float* W         = (const float*)d_in[2];
    float* io = (float*)d_out;

    const int n_nodes = in_sizes[0] / D;   // 100000
    const int n_tiles = n_nodes / 16;      // 6250 exact

    // Phase 1: one wave per node (R5 exact)
    {
        const int tpb = 256;
        const int blocks = (n_nodes * 64 + tpb - 1) / tpb;  // 25000
        ctx_kernel<<<dim3(blocks), dim3(tpb), 0, stream>>>(
            self_vecs, neigh, io, n_nodes);
    }
    // Phase 2: 16-node tiles on the matrix pipe
    {
        const int tpb = 256;      // 4 waves
        const int blocks = 1024;  // 4 blocks/CU
        const int total_waves = blocks * (tpb / 64);
        mlp_mfma<<<dim3(blocks), dim3(tpb), 0, stream>>>(
            W, io, n_tiles, total_waves);
    }
}